// Round 4
// baseline (786.033 us; speedup 1.0000x reference)
//
#include <hip/hip_runtime.h>
#include <hip/hip_cooperative_groups.h>

namespace cg = cooperative_groups;

#define IN_NUM 1152
#define OUT_NUM 10
#define OUT_DIM 16
#define IN_DIM 8
#define NB 256
#define KTOT 9216

// workspace float offsets
#define OFF_SPART 0
#define SZ_SPART (96 * OUT_NUM * OUT_DIM * NB)        // 3,932,160
#define OFF_VT (OFF_SPART + SZ_SPART)
#define SZ_VT (NB * OUT_NUM * OUT_DIM)                // 40,960
#define OFF_BP (OFF_VT + SZ_VT)
#define SZ_BP (16 * IN_NUM * OUT_NUM)                 // 184,320
#define OFF_WT (OFF_BP + SZ_BP)
#define SZ_WT (OUT_NUM * OUT_DIM * IN_DIM * IN_NUM)   // 1,474,560

#define SMEM_FLOATS 5792   // 23,168 B per block

// ---- phase 0: Wt[j][d][c][i] = W[i][j][d][c], 360 tiles of 32 i-rows ----
__device__ __forceinline__ void phase0(float* smem, int t, int bid, int grid,
                                       const float* __restrict__ W, float* __restrict__ Wt) {
    float (*lds)[129] = (float (*)[129])smem;
    int r0 = t >> 5, c4 = t & 31;
    for (int w = bid; w < 360; w += grid) {
        int itile = w / 10, j = w - itile * 10;
        int i0 = itile * 32;
        __syncthreads();
#pragma unroll
        for (int rr = 0; rr < 4; ++rr) {
            int r = rr * 8 + r0;
            float4 w4 = *reinterpret_cast<const float4*>(
                &W[(size_t)(i0 + r) * 1280 + j * 128 + c4 * 4]);
            lds[r][c4 * 4 + 0] = w4.x; lds[r][c4 * 4 + 1] = w4.y;
            lds[r][c4 * 4 + 2] = w4.z; lds[r][c4 * 4 + 3] = w4.w;
        }
        __syncthreads();
        int ii = t & 31, dcq = t >> 5;
#pragma unroll
        for (int rr = 0; rr < 16; ++rr) {
            int dc = rr * 8 + dcq;
            Wt[(size_t)(j * 128 + dc) * IN_NUM + i0 + ii] = lds[ii][dc];
        }
    }
}

// ---- phase 1: spart[isp][j][d][b] = sum_{k in chunk} c[i,j]W[i,j,d,c] * x[b][k] ----
__device__ __forceinline__ void phase1(float* smem, int t, int w, int it,
                                       const float* __restrict__ x, const float* __restrict__ Wt,
                                       const float* __restrict__ bp, float* __restrict__ spart) {
    int g8 = w / 80, r = w - g8 * 80;
    int j = r >> 3, isp = g8 * 8 + (r & 7);   // co-locate same-isp blocks on an XCD
    int cch = isp / 12;
    int i0 = (isp - cch * 12) * 96;
    int k0 = isp * 96;
    float (*xt)[260] = (float (*)[260])smem;           // 16 x 260 = 4160
    float (*at)[16]  = (float (*)[16])(smem + 4160);   // 96 x 16 = 1536
    float* ldc = smem + 5696;                          // 96
    __syncthreads();   // protect previous work-item's smem reads
    if (t < 96) {
        float cv;
        if (it == 0) {
            cv = 0.1f;
        } else {
            int i = i0 + t;
            float bt_[OUT_NUM];
#pragma unroll
            for (int jp = 0; jp < OUT_NUM; ++jp) bt_[jp] = 0.f;
#pragma unroll
            for (int row = 0; row < 16; ++row) {
                const float* p = &bp[((size_t)row * IN_NUM + i) * OUT_NUM];
#pragma unroll
                for (int jp = 0; jp < OUT_NUM; ++jp) bt_[jp] += p[jp];
            }
            float m = -1e30f;
#pragma unroll
            for (int jp = 0; jp < OUT_NUM; ++jp) { bt_[jp] *= (1.f / NB); m = fmaxf(m, bt_[jp]); }
            float s = 0.f;
#pragma unroll
            for (int jp = 0; jp < OUT_NUM; ++jp) { bt_[jp] = __expf(bt_[jp] - m); s += bt_[jp]; }
            cv = bt_[j] / s;
        }
        ldc[t] = cv;
    }
    __syncthreads();
    for (int e = t; e < 1536; e += 256) {
        int d = e / 96, kk = e - d * 96;
        at[kk][d] = ldc[kk] * Wt[(size_t)(j * 16 + d) * KTOT + cch * IN_NUM + i0 + kk];
    }
    int bb = t & 63, dg = t >> 6;
    int q4 = t & 3, row = t >> 2;
    float acc[16];
#pragma unroll
    for (int q = 0; q < 16; ++q) acc[q] = 0.f;
    for (int ch = 0; ch < 6; ++ch) {
        __syncthreads();
#pragma unroll
        for (int rr = 0; rr < 4; ++rr) {
            int b = rr * 64 + row;
            float4 xv = *reinterpret_cast<const float4*>(
                &x[(size_t)b * KTOT + k0 + ch * 16 + q4 * 4]);
            xt[q4 * 4 + 0][b] = xv.x; xt[q4 * 4 + 1][b] = xv.y;
            xt[q4 * 4 + 2][b] = xv.z; xt[q4 * 4 + 3][b] = xv.w;
        }
        __syncthreads();
#pragma unroll
        for (int kk = 0; kk < 16; ++kk) {
            float4 xv = *reinterpret_cast<const float4*>(&xt[kk][bb * 4]);
            float4 a4 = *reinterpret_cast<const float4*>(&at[ch * 16 + kk][dg * 4]);
            acc[0]  += a4.x * xv.x; acc[1]  += a4.x * xv.y; acc[2]  += a4.x * xv.z; acc[3]  += a4.x * xv.w;
            acc[4]  += a4.y * xv.x; acc[5]  += a4.y * xv.y; acc[6]  += a4.y * xv.z; acc[7]  += a4.y * xv.w;
            acc[8]  += a4.z * xv.x; acc[9]  += a4.z * xv.y; acc[10] += a4.z * xv.z; acc[11] += a4.z * xv.w;
            acc[12] += a4.w * xv.x; acc[13] += a4.w * xv.y; acc[14] += a4.w * xv.z; acc[15] += a4.w * xv.w;
        }
    }
    float* sp = spart + (size_t)(isp * OUT_NUM + j) * (OUT_DIM * NB);
#pragma unroll
    for (int dd = 0; dd < 4; ++dd) {
        float4 o;
        o.x = acc[dd * 4 + 0]; o.y = acc[dd * 4 + 1];
        o.z = acc[dd * 4 + 2]; o.w = acc[dd * 4 + 3];
        *reinterpret_cast<float4*>(&sp[(dg * 4 + dd) * NB + bb * 4]) = o;
    }
}

// ---- phase 2: reduce spart over isp, squash, write dst[b][j][d] ----
__device__ __forceinline__ void phase2(float* smem, int t, int w,
                                       const float* __restrict__ spart, float* __restrict__ dst) {
    float (*red)[32][17] = (float (*)[32][17])smem;    // 4352
    float (*nrm)[9] = (float (*)[9])(smem + 4352);     // 288
    float* cf = smem + 4640;                           // 32
    int j = w >> 3, bt2 = w & 7;
    int ie = t >> 5, bb = t & 31;
    int b = bt2 * 32 + bb;
    __syncthreads();
    float acc[16];
#pragma unroll
    for (int d = 0; d < 16; ++d) acc[d] = 0.f;
    for (int q = 0; q < 12; ++q) {
        int isp = ie * 12 + q;
        const float* sp = spart + (size_t)(isp * OUT_NUM + j) * (OUT_DIM * NB) + b;
#pragma unroll
        for (int d = 0; d < 16; ++d) acc[d] += sp[d * NB];
    }
#pragma unroll
    for (int d = 0; d < 16; ++d) red[ie][bb][d] = acc[d];
    __syncthreads();
    int bb2 = t >> 3, dp = t & 7;
    float s0 = 0.f, s1 = 0.f;
#pragma unroll
    for (int e = 0; e < 8; ++e) { s0 += red[e][bb2][dp * 2]; s1 += red[e][bb2][dp * 2 + 1]; }
    nrm[bb2][dp] = s0 * s0 + s1 * s1;
    __syncthreads();
    if (t < 32) {
        float qn = 0.f;
#pragma unroll
        for (int d = 0; d < 8; ++d) qn += nrm[t][d];
        cf[t] = qn / ((1.f + qn) * sqrtf(qn));
    }
    __syncthreads();
    float cs = cf[bb2];
    float* o = dst + (size_t)(bt2 * 32 + bb2) * (OUT_NUM * OUT_DIM) + j * OUT_DIM + dp * 2;
    o[0] = s0 * cs;
    o[1] = s1 * cs;
}

// ---- phase 3: bp[bh][c][i][j] = prev + sum_d Wt[j][d][c][i] * sum_b vt[b][j][d]*x[b][k] ----
__device__ __forceinline__ void phase3(int u, int t, int it,
                                       const float* __restrict__ x, const float* __restrict__ vt,
                                       const float* __restrict__ Wt, float* __restrict__ bp) {
    int g8 = u / 160, r = u - g8 * 160;
    int jb = r >> 3;
    int kt = g8 * 8 + (r & 7);
    int j = jb >> 1, bh = jb & 1;
    int lane = t & 63;
    int k = kt * 64 + lane;
    int c = k / IN_NUM;
    int i = k - c * IN_NUM;
    const float* xk = x + k;
    const float* vj = vt + j * OUT_DIM;
    float acc[16];
#pragma unroll
    for (int d = 0; d < 16; ++d) acc[d] = 0.f;
    int b0 = bh * 128;
#pragma unroll 4
    for (int b = b0; b < b0 + 128; ++b) {
        float xv = xk[(size_t)b * KTOT];
        const float* vb = vj + (size_t)b * (OUT_NUM * OUT_DIM);   // wave-uniform
#pragma unroll
        for (int d = 0; d < 16; ++d) acc[d] += vb[d] * xv;
    }
    float bs = 0.f;
#pragma unroll
    for (int d = 0; d < 16; ++d)
        bs += acc[d] * Wt[((size_t)(j * OUT_DIM + d) * IN_DIM + c) * IN_NUM + i];
    size_t idx = ((size_t)(bh * IN_DIM + c) * IN_NUM + i) * OUT_NUM + j;
    float prev = (it == 0) ? 0.f : bp[idx];
    bp[idx] = prev + bs;
}

// ================= cooperative fused kernel =================
__global__ __launch_bounds__(256, 4) void k_fused(const float* __restrict__ x,
                                                  const float* __restrict__ W,
                                                  float* __restrict__ out,
                                                  float* __restrict__ ws) {
    cg::grid_group gg = cg::this_grid();
    __shared__ float smem[SMEM_FLOATS];
    float* spart = ws + OFF_SPART;
    float* vt    = ws + OFF_VT;
    float* bp    = ws + OFF_BP;
    float* Wt    = ws + OFF_WT;
    int t = threadIdx.x, bid = blockIdx.x, G = gridDim.x;

    phase0(smem, t, bid, G, W, Wt);
    gg.sync();
    for (int it = 0; it < 3; ++it) {
        for (int w = bid; w < 960; w += G) phase1(smem, t, w, it, x, Wt, bp, spart);
        gg.sync();
        float* dst = (it == 2) ? out : vt;
        for (int w = bid; w < 80; w += G) phase2(smem, t, w, spart, dst);
        if (it == 2) return;
        gg.sync();
        for (int w = bid; w < 720; w += G) phase3(w * 4 + (t >> 6), t, it, x, vt, Wt, bp);
        gg.sync();
    }
}

// ================= fallback (ordinary launches) =================
__global__ __launch_bounds__(256, 4) void k_p0(const float* __restrict__ W, float* __restrict__ ws) {
    __shared__ float smem[SMEM_FLOATS];
    phase0(smem, threadIdx.x, blockIdx.x, gridDim.x, W, ws + OFF_WT);
}
__global__ __launch_bounds__(256, 4) void k_p1(const float* __restrict__ x, float* __restrict__ ws, int it) {
    __shared__ float smem[SMEM_FLOATS];
    for (int w = blockIdx.x; w < 960; w += gridDim.x)
        phase1(smem, threadIdx.x, w, it, x, ws + OFF_WT, ws + OFF_BP, ws + OFF_SPART);
}
__global__ __launch_bounds__(256, 4) void k_p2(const float* __restrict__ ws, float* __restrict__ dst) {
    __shared__ float smem[SMEM_FLOATS];
    for (int w = blockIdx.x; w < 80; w += gridDim.x)
        phase2(smem, threadIdx.x, w, ws + OFF_SPART, dst);
}
__global__ __launch_bounds__(256, 4) void k_p3(const float* __restrict__ x, float* __restrict__ ws, int it) {
    for (int w = blockIdx.x; w < 720; w += gridDim.x)
        phase3(w * 4 + (threadIdx.x >> 6), threadIdx.x, it, x, ws + OFF_VT, ws + OFF_WT, ws + OFF_BP);
}

extern "C" void kernel_launch(void* const* d_in, const int* in_sizes, int n_in,
                              void* d_out, int out_size, void* d_ws, size_t ws_size,
                              hipStream_t stream) {
    const float* x = (const float*)d_in[0];   // [256][8][1152]
    const float* W = (const float*)d_in[1];   // [1152][10][16][8]
    float* out = (float*)d_out;               // [256][10][16][1]
    float* ws = (float*)d_ws;

    int occ = 0;
    hipError_t oe = hipOccupancyMaxActiveBlocksPerMultiprocessor(&occ, (const void*)k_fused, 256, 0);
    int grid = (oe == hipSuccess && occ >= 1) ? (occ * 256) : 256;
    if (grid > 960) grid = 960;

    void* args[] = {(void*)&x, (void*)&W, (void*)&out, (void*)&ws};
    hipError_t e = hipLaunchCooperativeKernel((void*)k_fused, dim3(grid), dim3(256), args, 0, stream);
    if (e != hipSuccess) {
        // ordinary-launch fallback: identical phase code, kernel boundaries as syncs
        k_p0<<<dim3(360), dim3(256), 0, stream>>>(W, ws);
        for (int it = 0; it < 3; ++it) {
            k_p1<<<dim3(960), dim3(256), 0, stream>>>(x, ws, it);
            k_p2<<<dim3(80), dim3(256), 0, stream>>>(ws, it == 2 ? out : (ws + OFF_VT));
            if (it < 2) k_p3<<<dim3(720), dim3(256), 0, stream>>>(x, ws, it);
        }
    }
}

// Round 5
// 186.802 us; speedup vs baseline: 4.2078x; 4.2078x over previous
//
#include <hip/hip_runtime.h>

#define IN_NUM 1152
#define OUT_NUM 10
#define OUT_DIM 16
#define IN_DIM 8
#define NB 256
#define KTOT 9216

// workspace float offsets
#define OFF_SPART 0
#define SZ_SPART (96 * OUT_NUM * OUT_DIM * NB)        // 3,932,160
#define OFF_VT (OFF_SPART + SZ_SPART)
#define SZ_VT (NB * OUT_NUM * OUT_DIM)                // 40,960
#define OFF_BP (OFF_VT + SZ_VT)
#define SZ_BP (16 * IN_NUM * OUT_NUM)                 // 184,320
#define OFF_WT (OFF_BP + SZ_BP)
#define SZ_WT (OUT_NUM * OUT_DIM * IN_DIM * IN_NUM)   // 1,474,560

#define SMEM_FLOATS 5792   // 23,168 B per block

// ---- phase 0: Wt[j][d][c][i] = W[i][j][d][c], 360 tiles of 32 i-rows ----
__device__ __forceinline__ void phase0(float* smem, int t, int w,
                                       const float* __restrict__ W, float* __restrict__ Wt) {
    float (*lds)[129] = (float (*)[129])smem;
    int r0 = t >> 5, c4 = t & 31;
    int itile = w / 10, j = w - itile * 10;
    int i0 = itile * 32;
#pragma unroll
    for (int rr = 0; rr < 4; ++rr) {
        int r = rr * 8 + r0;
        float4 w4 = *reinterpret_cast<const float4*>(
            &W[(size_t)(i0 + r) * 1280 + j * 128 + c4 * 4]);
        lds[r][c4 * 4 + 0] = w4.x; lds[r][c4 * 4 + 1] = w4.y;
        lds[r][c4 * 4 + 2] = w4.z; lds[r][c4 * 4 + 3] = w4.w;
    }
    __syncthreads();
    int ii = t & 31, dcq = t >> 5;
#pragma unroll
    for (int rr = 0; rr < 16; ++rr) {
        int dc = rr * 8 + dcq;
        Wt[(size_t)(j * 128 + dc) * IN_NUM + i0 + ii] = lds[ii][dc];
    }
}

// ---- phase 1: spart[isp][j][d][b] = sum_{k in chunk} c[i,j]W[i,j,d,c] * x[b][k] ----
__device__ __forceinline__ void phase1(float* smem, int t, int w, int it,
                                       const float* __restrict__ x, const float* __restrict__ Wt,
                                       const float* __restrict__ bp, float* __restrict__ spart) {
    int g8 = w / 80, r = w - g8 * 80;
    int j = r >> 3, isp = g8 * 8 + (r & 7);   // same-isp blocks 8 apart -> same XCD
    int cch = isp / 12;
    int i0 = (isp - cch * 12) * 96;
    int k0 = isp * 96;
    float (*xt)[260] = (float (*)[260])smem;           // 16 x 260 = 4160
    float (*at)[16]  = (float (*)[16])(smem + 4160);   // 96 x 16 = 1536
    float* ldc = smem + 5696;                          // 96
    if (t < 96) {
        float cv;
        if (it == 0) {
            cv = 0.1f;
        } else {
            int i = i0 + t;
            float bt_[OUT_NUM];
#pragma unroll
            for (int jp = 0; jp < OUT_NUM; ++jp) bt_[jp] = 0.f;
#pragma unroll
            for (int row = 0; row < 16; ++row) {
                const float* p = &bp[((size_t)row * IN_NUM + i) * OUT_NUM];
#pragma unroll
                for (int jp = 0; jp < OUT_NUM; ++jp) bt_[jp] += p[jp];
            }
            float m = -1e30f;
#pragma unroll
            for (int jp = 0; jp < OUT_NUM; ++jp) { bt_[jp] *= (1.f / NB); m = fmaxf(m, bt_[jp]); }
            float s = 0.f;
#pragma unroll
            for (int jp = 0; jp < OUT_NUM; ++jp) { bt_[jp] = __expf(bt_[jp] - m); s += bt_[jp]; }
            cv = bt_[j] / s;
        }
        ldc[t] = cv;
    }
    __syncthreads();
    for (int e = t; e < 1536; e += 256) {
        int d = e / 96, kk = e - d * 96;
        at[kk][d] = ldc[kk] * Wt[(size_t)(j * 16 + d) * KTOT + cch * IN_NUM + i0 + kk];
    }
    int bb = t & 63, dg = t >> 6;
    int q4 = t & 3, row = t >> 2;
    float acc[16];
#pragma unroll
    for (int q = 0; q < 16; ++q) acc[q] = 0.f;
    for (int ch = 0; ch < 6; ++ch) {
        __syncthreads();
#pragma unroll
        for (int rr = 0; rr < 4; ++rr) {
            int b = rr * 64 + row;
            float4 xv = *reinterpret_cast<const float4*>(
                &x[(size_t)b * KTOT + k0 + ch * 16 + q4 * 4]);
            xt[q4 * 4 + 0][b] = xv.x; xt[q4 * 4 + 1][b] = xv.y;
            xt[q4 * 4 + 2][b] = xv.z; xt[q4 * 4 + 3][b] = xv.w;
        }
        __syncthreads();
#pragma unroll
        for (int kk = 0; kk < 16; ++kk) {
            float4 xv = *reinterpret_cast<const float4*>(&xt[kk][bb * 4]);
            float4 a4 = *reinterpret_cast<const float4*>(&at[ch * 16 + kk][dg * 4]);  // wave-uniform -> LDS broadcast
            acc[0]  += a4.x * xv.x; acc[1]  += a4.x * xv.y; acc[2]  += a4.x * xv.z; acc[3]  += a4.x * xv.w;
            acc[4]  += a4.y * xv.x; acc[5]  += a4.y * xv.y; acc[6]  += a4.y * xv.z; acc[7]  += a4.y * xv.w;
            acc[8]  += a4.z * xv.x; acc[9]  += a4.z * xv.y; acc[10] += a4.z * xv.z; acc[11] += a4.z * xv.w;
            acc[12] += a4.w * xv.x; acc[13] += a4.w * xv.y; acc[14] += a4.w * xv.z; acc[15] += a4.w * xv.w;
        }
    }
    float* sp = spart + (size_t)(isp * OUT_NUM + j) * (OUT_DIM * NB);
#pragma unroll
    for (int dd = 0; dd < 4; ++dd) {
        float4 o;
        o.x = acc[dd * 4 + 0]; o.y = acc[dd * 4 + 1];
        o.z = acc[dd * 4 + 2]; o.w = acc[dd * 4 + 3];
        *reinterpret_cast<float4*>(&sp[(dg * 4 + dd) * NB + bb * 4]) = o;
    }
}

// ---- phase 2: reduce spart over isp, squash, write dst[b][j][d] ----
__device__ __forceinline__ void phase2(float* smem, int t, int w,
                                       const float* __restrict__ spart, float* __restrict__ dst) {
    float (*red)[32][17] = (float (*)[32][17])smem;    // 4352
    float (*nrm)[9] = (float (*)[9])(smem + 4352);     // 288
    float* cf = smem + 4640;                           // 32
    int j = w >> 3, bt2 = w & 7;
    int ie = t >> 5, bb = t & 31;
    int b = bt2 * 32 + bb;
    float acc[16];
#pragma unroll
    for (int d = 0; d < 16; ++d) acc[d] = 0.f;
    for (int q = 0; q < 12; ++q) {
        int isp = ie * 12 + q;
        const float* sp = spart + (size_t)(isp * OUT_NUM + j) * (OUT_DIM * NB) + b;
#pragma unroll
        for (int d = 0; d < 16; ++d) acc[d] += sp[d * NB];
    }
#pragma unroll
    for (int d = 0; d < 16; ++d) red[ie][bb][d] = acc[d];
    __syncthreads();
    int bb2 = t >> 3, dp = t & 7;
    float s0 = 0.f, s1 = 0.f;
#pragma unroll
    for (int e = 0; e < 8; ++e) { s0 += red[e][bb2][dp * 2]; s1 += red[e][bb2][dp * 2 + 1]; }
    nrm[bb2][dp] = s0 * s0 + s1 * s1;
    __syncthreads();
    if (t < 32) {
        float qn = 0.f;
#pragma unroll
        for (int d = 0; d < 8; ++d) qn += nrm[t][d];
        cf[t] = qn / ((1.f + qn) * sqrtf(qn));
    }
    __syncthreads();
    float cs = cf[bb2];
    float* o = dst + (size_t)(bt2 * 32 + bb2) * (OUT_NUM * OUT_DIM) + j * OUT_DIM + dp * 2;
    o[0] = s0 * cs;
    o[1] = s1 * cs;
}

// ---- phase 3: bp[bh][c][i][j] = prev + sum_d Wt[j][d][c][i] * sum_b vt[b][j][d]*x[b][k] ----
__device__ __forceinline__ void phase3(int u, int t, int it,
                                       const float* __restrict__ x, const float* __restrict__ vt,
                                       const float* __restrict__ Wt, float* __restrict__ bp) {
    int g8 = u / 160, r = u - g8 * 160;
    int jb = r >> 3;
    int kt = g8 * 8 + (r & 7);
    int j = jb >> 1, bh = jb & 1;
    int lane = t & 63;
    int k = kt * 64 + lane;
    int c = k / IN_NUM;
    int i = k - c * IN_NUM;
    const float* xk = x + k;
    const float* vj = vt + j * OUT_DIM;
    float acc[16];
#pragma unroll
    for (int d = 0; d < 16; ++d) acc[d] = 0.f;
    int b0 = bh * 128;
#pragma unroll 4
    for (int b = b0; b < b0 + 128; ++b) {
        float xv = xk[(size_t)b * KTOT];
        const float* vb = vj + (size_t)b * (OUT_NUM * OUT_DIM);   // wave-uniform
#pragma unroll
        for (int d = 0; d < 16; ++d) acc[d] += vb[d] * xv;
    }
    float bs = 0.f;
#pragma unroll
    for (int d = 0; d < 16; ++d)
        bs += acc[d] * Wt[((size_t)(j * OUT_DIM + d) * IN_DIM + c) * IN_NUM + i];
    size_t idx = ((size_t)(bh * IN_DIM + c) * IN_NUM + i) * OUT_NUM + j;
    float prev = (it == 0) ? 0.f : bp[idx];
    bp[idx] = prev + bs;
}

// ================= ordinary kernels =================
__global__ __launch_bounds__(256, 4) void k_p0(const float* __restrict__ W, float* __restrict__ ws) {
    __shared__ float smem[SMEM_FLOATS];
    phase0(smem, threadIdx.x, blockIdx.x, W, ws + OFF_WT);
}
__global__ __launch_bounds__(256, 4) void k_p1(const float* __restrict__ x, float* __restrict__ ws, int it) {
    __shared__ float smem[SMEM_FLOATS];
    phase1(smem, threadIdx.x, blockIdx.x, it, x, ws + OFF_WT, ws + OFF_BP, ws + OFF_SPART);
}
__global__ __launch_bounds__(256, 4) void k_p2(const float* __restrict__ ws, float* __restrict__ dst) {
    __shared__ float smem[SMEM_FLOATS];
    phase2(smem, threadIdx.x, blockIdx.x, ws + OFF_SPART, dst);
}
__global__ __launch_bounds__(256, 4) void k_p3(const float* __restrict__ x, float* __restrict__ ws, int it) {
    phase3(blockIdx.x * 4 + (threadIdx.x >> 6), threadIdx.x, it, x, ws + OFF_VT, ws + OFF_WT, ws + OFF_BP);
}

extern "C" void kernel_launch(void* const* d_in, const int* in_sizes, int n_in,
                              void* d_out, int out_size, void* d_ws, size_t ws_size,
                              hipStream_t stream) {
    const float* x = (const float*)d_in[0];   // [256][8][1152]
    const float* W = (const float*)d_in[1];   // [1152][10][16][8]
    float* out = (float*)d_out;               // [256][10][16][1]
    float* ws = (float*)d_ws;

    k_p0<<<dim3(360), dim3(256), 0, stream>>>(W, ws);
    for (int it = 0; it < 3; ++it) {
        k_p1<<<dim3(960), dim3(256), 0, stream>>>(x, ws, it);
        k_p2<<<dim3(80), dim3(256), 0, stream>>>(ws, it == 2 ? out : (ws + OFF_VT));
        if (it < 2) k_p3<<<dim3(720), dim3(256), 0, stream>>>(x, ws, it);
    }
}

// Round 6
// 122.506 us; speedup vs baseline: 6.4163x; 1.5248x over previous
//
#include <hip/hip_runtime.h>

#define IN_NUM 1152
#define OUT_NUM 10
#define OUT_DIM 16
#define IN_DIM 8
#define NB 256
#define KTOT 9216

// workspace float offsets
#define OFF_SPART 0
#define SZ_SPART (96 * OUT_NUM * OUT_DIM * NB)        // 3,932,160
#define OFF_VT (OFF_SPART + SZ_SPART)
#define SZ_VT (NB * OUT_NUM * OUT_DIM)                // 40,960
#define OFF_BP (OFF_VT + SZ_VT)
#define SZ_BP (32 * IN_NUM * OUT_NUM)                 // 368,640 (4 b-quarters x 8 c)
#define OFF_WT (OFF_BP + SZ_BP)
#define SZ_WT (OUT_NUM * OUT_DIM * IN_DIM * IN_NUM)   // 1,474,560

#define SMEM_FLOATS 5792   // 23,168 B per block

// ---- phase 0: Wt[j][d][c][i] = W[i][j][d][c], 360 tiles of 32 i-rows ----
__device__ __forceinline__ void phase0(float* smem, int t, int w,
                                       const float* __restrict__ W, float* __restrict__ Wt) {
    float (*lds)[129] = (float (*)[129])smem;
    int r0 = t >> 5, c4 = t & 31;
    int itile = w / 10, j = w - itile * 10;
    int i0 = itile * 32;
#pragma unroll
    for (int rr = 0; rr < 4; ++rr) {
        int r = rr * 8 + r0;
        float4 w4 = *reinterpret_cast<const float4*>(
            &W[(size_t)(i0 + r) * 1280 + j * 128 + c4 * 4]);
        lds[r][c4 * 4 + 0] = w4.x; lds[r][c4 * 4 + 1] = w4.y;
        lds[r][c4 * 4 + 2] = w4.z; lds[r][c4 * 4 + 3] = w4.w;
    }
    __syncthreads();
    int ii = t & 31, dcq = t >> 5;
#pragma unroll
    for (int rr = 0; rr < 16; ++rr) {
        int dc = rr * 8 + dcq;
        Wt[(size_t)(j * 128 + dc) * IN_NUM + i0 + ii] = lds[ii][dc];
    }
}

// ---- phase 1: spart[isp][j][d][b] = sum_{k in chunk} c[i,j]W[i,j,d,c] * x[b][k] ----
__device__ __forceinline__ void phase1(float* smem, int t, int w, int it,
                                       const float* __restrict__ x, const float* __restrict__ Wt,
                                       const float* __restrict__ bp, float* __restrict__ spart) {
    int g8 = w / 80, r = w - g8 * 80;
    int j = r >> 3, isp = g8 * 8 + (r & 7);   // same-isp blocks 8 apart -> same XCD
    int cch = isp / 12;
    int i0 = (isp - cch * 12) * 96;
    int k0 = isp * 96;
    float (*xt)[260] = (float (*)[260])smem;           // 16 x 260 = 4160
    float (*at)[16]  = (float (*)[16])(smem + 4160);   // 96 x 16 = 1536
    float* ldc = smem + 5696;                          // 96
    if (t < 96) {
        float cv;
        if (it == 0) {
            cv = 0.1f;
        } else {
            int i = i0 + t;
            float bt_[OUT_NUM];
#pragma unroll
            for (int jp = 0; jp < OUT_NUM; ++jp) bt_[jp] = 0.f;
#pragma unroll
            for (int row = 0; row < 32; ++row) {   // 4 quarters x 8 c partial rows
                const float* p = &bp[((size_t)row * IN_NUM + i) * OUT_NUM];
#pragma unroll
                for (int jp = 0; jp < OUT_NUM; ++jp) bt_[jp] += p[jp];
            }
            float m = -1e30f;
#pragma unroll
            for (int jp = 0; jp < OUT_NUM; ++jp) { bt_[jp] *= (1.f / NB); m = fmaxf(m, bt_[jp]); }
            float s = 0.f;
#pragma unroll
            for (int jp = 0; jp < OUT_NUM; ++jp) { bt_[jp] = __expf(bt_[jp] - m); s += bt_[jp]; }
            cv = bt_[j] / s;
        }
        ldc[t] = cv;
    }
    __syncthreads();
    for (int e = t; e < 1536; e += 256) {
        int d = e / 96, kk = e - d * 96;
        at[kk][d] = ldc[kk] * Wt[(size_t)(j * 16 + d) * KTOT + cch * IN_NUM + i0 + kk];
    }
    int bb = t & 63, dg = t >> 6;
    int q4 = t & 3, row = t >> 2;
    float acc[16];
#pragma unroll
    for (int q = 0; q < 16; ++q) acc[q] = 0.f;
    for (int ch = 0; ch < 6; ++ch) {
        __syncthreads();
#pragma unroll
        for (int rr = 0; rr < 4; ++rr) {
            int b = rr * 64 + row;
            float4 xv = *reinterpret_cast<const float4*>(
                &x[(size_t)b * KTOT + k0 + ch * 16 + q4 * 4]);
            xt[q4 * 4 + 0][b] = xv.x; xt[q4 * 4 + 1][b] = xv.y;
            xt[q4 * 4 + 2][b] = xv.z; xt[q4 * 4 + 3][b] = xv.w;
        }
        __syncthreads();
#pragma unroll
        for (int kk = 0; kk < 16; ++kk) {
            float4 xv = *reinterpret_cast<const float4*>(&xt[kk][bb * 4]);
            float4 a4 = *reinterpret_cast<const float4*>(&at[ch * 16 + kk][dg * 4]);  // wave-uniform -> LDS broadcast
            acc[0]  += a4.x * xv.x; acc[1]  += a4.x * xv.y; acc[2]  += a4.x * xv.z; acc[3]  += a4.x * xv.w;
            acc[4]  += a4.y * xv.x; acc[5]  += a4.y * xv.y; acc[6]  += a4.y * xv.z; acc[7]  += a4.y * xv.w;
            acc[8]  += a4.z * xv.x; acc[9]  += a4.z * xv.y; acc[10] += a4.z * xv.z; acc[11] += a4.z * xv.w;
            acc[12] += a4.w * xv.x; acc[13] += a4.w * xv.y; acc[14] += a4.w * xv.z; acc[15] += a4.w * xv.w;
        }
    }
    float* sp = spart + (size_t)(isp * OUT_NUM + j) * (OUT_DIM * NB);
#pragma unroll
    for (int dd = 0; dd < 4; ++dd) {
        float4 o;
        o.x = acc[dd * 4 + 0]; o.y = acc[dd * 4 + 1];
        o.z = acc[dd * 4 + 2]; o.w = acc[dd * 4 + 3];
        *reinterpret_cast<float4*>(&sp[(dg * 4 + dd) * NB + bb * 4]) = o;
    }
}

// ---- phase 2: reduce spart over isp, squash, write dst[b][j][d] ----
__device__ __forceinline__ void phase2(float* smem, int t, int w,
                                       const float* __restrict__ spart, float* __restrict__ dst) {
    float (*red)[32][17] = (float (*)[32][17])smem;    // 4352
    float (*nrm)[9] = (float (*)[9])(smem + 4352);     // 288
    float* cf = smem + 4640;                           // 32
    int j = w >> 3, bt2 = w & 7;
    int ie = t >> 5, bb = t & 31;
    int b = bt2 * 32 + bb;
    float acc[16];
#pragma unroll
    for (int d = 0; d < 16; ++d) acc[d] = 0.f;
    for (int q = 0; q < 12; ++q) {
        int isp = ie * 12 + q;
        const float* sp = spart + (size_t)(isp * OUT_NUM + j) * (OUT_DIM * NB) + b;
#pragma unroll
        for (int d = 0; d < 16; ++d) acc[d] += sp[d * NB];
    }
#pragma unroll
    for (int d = 0; d < 16; ++d) red[ie][bb][d] = acc[d];
    __syncthreads();
    int bb2 = t >> 3, dp = t & 7;
    float s0 = 0.f, s1 = 0.f;
#pragma unroll
    for (int e = 0; e < 8; ++e) { s0 += red[e][bb2][dp * 2]; s1 += red[e][bb2][dp * 2 + 1]; }
    nrm[bb2][dp] = s0 * s0 + s1 * s1;
    __syncthreads();
    if (t < 32) {
        float qn = 0.f;
#pragma unroll
        for (int d = 0; d < 8; ++d) qn += nrm[t][d];
        cf[t] = qn / ((1.f + qn) * sqrtf(qn));
    }
    __syncthreads();
    float cs = cf[bb2];
    float* o = dst + (size_t)(bt2 * 32 + bb2) * (OUT_NUM * OUT_DIM) + j * OUT_DIM + dp * 2;
    o[0] = s0 * cs;
    o[1] = s1 * cs;
}

// ---- phase 3: bp[bq*8+c][i][j] = prev + sum_d Wt[j][d][k] * sum_{b in quarter} vt[b][j][d]*x[b][k] ----
// (j, bq) block-uniform -> vt loads scalarize (s_load); x loads coalesced; no LDS.
__device__ __forceinline__ void phase3(int u, int t, int it,
                                       const float* __restrict__ x, const float* __restrict__ vt,
                                       const float* __restrict__ Wt, float* __restrict__ bp) {
    int kt = u % 36;            // k-tile of 256
    int jq = u / 36;            // 0..39
    int j = jq >> 2, bq = jq & 3;
    int k = kt * 256 + t;
    int c = k / IN_NUM, i = k - c * IN_NUM;
    const float* xk = x + k + (size_t)(bq * 64) * KTOT;
    const float* vjb = vt + (size_t)(bq * 64) * (OUT_NUM * OUT_DIM) + j * OUT_DIM;
    float macc[16];
#pragma unroll
    for (int d = 0; d < 16; ++d) macc[d] = 0.f;
#pragma unroll 8
    for (int b = 0; b < 64; ++b) {
        float xv = xk[(size_t)b * KTOT];
        const float* vb = vjb + (size_t)b * (OUT_NUM * OUT_DIM);   // block-uniform -> s_load
#pragma unroll
        for (int d = 0; d < 16; ++d) macc[d] += vb[d] * xv;
    }
    float bs = 0.f;
#pragma unroll
    for (int d = 0; d < 16; ++d)
        bs += macc[d] * Wt[(size_t)(j * OUT_DIM + d) * KTOT + k];
    size_t idx = (size_t)(bq * 8 + c) * (IN_NUM * OUT_NUM) + (size_t)i * OUT_NUM + j;
    float prev = (it == 0) ? 0.f : bp[idx];
    bp[idx] = prev + bs;
}

// ================= ordinary kernels =================
__global__ __launch_bounds__(256, 4) void k_p0(const float* __restrict__ W, float* __restrict__ ws) {
    __shared__ float smem[SMEM_FLOATS];
    phase0(smem, threadIdx.x, blockIdx.x, W, ws + OFF_WT);
}
__global__ __launch_bounds__(256, 4) void k_p1(const float* __restrict__ x, float* __restrict__ ws, int it) {
    __shared__ float smem[SMEM_FLOATS];
    phase1(smem, threadIdx.x, blockIdx.x, it, x, ws + OFF_WT, ws + OFF_BP, ws + OFF_SPART);
}
__global__ __launch_bounds__(256, 4) void k_p2(const float* __restrict__ ws, float* __restrict__ dst) {
    __shared__ float smem[SMEM_FLOATS];
    phase2(smem, threadIdx.x, blockIdx.x, ws + OFF_SPART, dst);
}
__global__ __launch_bounds__(256) void k_p3(const float* __restrict__ x, float* __restrict__ ws, int it) {
    phase3(blockIdx.x, threadIdx.x, it, x, ws + OFF_VT, ws + OFF_WT, ws + OFF_BP);
}

extern "C" void kernel_launch(void* const* d_in, const int* in_sizes, int n_in,
                              void* d_out, int out_size, void* d_ws, size_t ws_size,
                              hipStream_t stream) {
    const float* x = (const float*)d_in[0];   // [256][8][1152]
    const float* W = (const float*)d_in[1];   // [1152][10][16][8]
    float* out = (float*)d_out;               // [256][10][16][1]
    float* ws = (float*)d_ws;

    k_p0<<<dim3(360), dim3(256), 0, stream>>>(W, ws);
    for (int it = 0; it < 3; ++it) {
        k_p1<<<dim3(960), dim3(256), 0, stream>>>(x, ws, it);
        k_p2<<<dim3(80), dim3(256), 0, stream>>>(ws, it == 2 ? out : (ws + OFF_VT));
        if (it < 2) k_p3<<<dim3(1440), dim3(256), 0, stream>>>(x, ws, it);
    }
}